// Round 15
// baseline (785.895 us; speedup 1.0000x reference)
//
#include <hip/hip_runtime.h>

typedef unsigned short u16;
typedef unsigned int   u32;
typedef unsigned long long u64;
typedef __attribute__((ext_vector_type(8))) short short8;
typedef __attribute__((ext_vector_type(4))) float f32x4;

#define DEVI __device__ __forceinline__

#define NPB 256      // nodes per coarse bucket
#define SHB 8        // log2(NPB)
#define BHB 64       // blocks for bucket hist/fill passes
#define PST 512      // stat phase-A blocks
#define LOG2E 1.44269504088896340736f

DEVI float bf2f(u16 u){ union{u32 i; float f;} x; x.i = ((u32)u)<<16; return x.f; }
DEVI u16 f2bf(float f){ union{float f; u32 i;} x; x.f = f;
  u32 r = (x.i + 0x7FFFu + ((x.i>>16)&1u))>>16; return (u16)r; }
DEVI float lrelu(float x){ return x > 0.f ? x : 0.2f*x; }
DEVI float exp2g(float x){ return __builtin_amdgcn_exp2f(x); }
DEVI float gload(const void* p, size_t i, int f32){
  return f32 ? ((const float*)p)[i] : bf2f(((const u16*)p)[i]);
}

// ---------------- merged prep ----------------
__global__ __launch_bounds__(256) void k_prep(const void* x, const void* W1,
    const void* W2, const void* as2, const void* ad2,
    const void* W3, const void* as3, const void* ad3,
    int* dflag, u16* Wt, u16* Wbd2, u16* Wbd3, float* prepF, int* cnts)
{
  __shared__ int sf32;
  if (threadIdx.x == 0){
    const u16* p = (const u16*)x;
    int hits = 0;
    for (int j = 0; j < 512; j++){
      u16 e = (p[j] >> 7) & 0xFF;
      if (e >= 0xC0) hits++;
    }
    sf32 = hits ? 1 : 0;
    if (blockIdx.x == 0) *dflag = sf32;
  }
  __syncthreads();
  const int f32 = sf32;
  int b = blockIdx.x, t = threadIdx.x;
  if (b < 16){
    for (int i = b*256 + t; i < 128*128; i += 16*256){
      int k = i >> 7, nn = i & 127;
      Wt[nn*128 + k] = f2bf(gload(W1, i, f32));
    }
  } else if (b == 16){
    for (int i = t; i < 64*96; i += 256){
      int r = i/96, m = i - r*96;
      int h = r >> 4, k = r & 15;
      float v = ((m/24) == h) ? gload(W2, k*96 + m, f32) : 0.f;
      Wbd2[i] = f2bf(v);
    }
    if (t < 64){
      int h = t >> 4, k = t & 15;
      float s = 0.f, d = 0.f;
      for (int c = 0; c < 24; c++){
        float w = gload(W2, k*96 + h*24 + c, f32);
        s = fmaf(w, gload(as2, h*24 + c, f32), s);
        d = fmaf(w, gload(ad2, h*24 + c, f32), d);
      }
      prepF[t] = s; prepF[64 + t] = d;
    }
  } else {
    for (int i = t; i < 48*64; i += 256){
      int r = i >> 6, m = i & 63;
      int h = r/24, k = r - h*24;
      float v = ((m >> 5) == h) ? gload(W3, k*64 + m, f32) : 0.f;
      Wbd3[i] = f2bf(v);
    }
    if (t < 48){
      int h = t/24, k = t - h*24;
      float s = 0.f, d = 0.f;
      for (int c = 0; c < 32; c++){
        float w = gload(W3, k*64 + h*32 + c, f32);
        s = fmaf(w, gload(as3, h*32 + c, f32), s);
        d = fmaf(w, gload(ad3, h*32 + c, f32), d);
      }
      prepF[128 + t] = s; prepF[176 + t] = d;
    }
    if (t >= 64 && t < 72) cnts[t - 64] = 0;
  }
}

// ---------------- CSR build ----------------
__global__ __launch_bounds__(1024) void k_bhist(const int* ei, int E, int* hist, int NB){
  __shared__ int lh[512];
  for (int b = threadIdx.x; b < NB; b += 1024) lh[b] = 0;
  __syncthreads();
  for (int e = blockIdx.x*1024 + threadIdx.x; e < E; e += BHB*1024)
    atomicAdd(&lh[((u32)ei[E + e]) >> SHB], 1);
  __syncthreads();
  for (int b = threadIdx.x; b < NB; b += 1024) hist[blockIdx.x*NB + b] = lh[b];
}

__global__ __launch_bounds__(256) void k_btotW(const int* hist, int* tot, int NB){
  int wv = threadIdx.x >> 6, lane = threadIdx.x & 63;
  int b = blockIdx.x*4 + wv;
  if (b >= NB) return;
  int v = hist[lane*NB + b];
  #pragma unroll
  for (int st = 1; st < 64; st <<= 1) v += __shfl_xor(v, st);
  if (lane == 0) tot[b] = v;
}

__global__ __launch_bounds__(512) void k_bscan(const int* tot, int* base, int* coff, int NB, int N){
  __shared__ int l[512];
  int t = threadIdx.x;
  int v = (t < NB) ? tot[t] : 0;
  l[t] = v; __syncthreads();
  for (int st = 1; st < 512; st <<= 1){
    int a = (t >= st) ? l[t - st] : 0;
    __syncthreads();
    l[t] += a;
    __syncthreads();
  }
  if (t < NB) base[t] = l[t] - v;
  if (t == 511){ base[NB] = l[511]; coff[N] = l[511]; }
}

__global__ __launch_bounds__(256) void k_bcurW(int* hist, const int* base, int NB){
  int wv = threadIdx.x >> 6, lane = threadIdx.x & 63;
  int b = blockIdx.x*4 + wv;
  if (b >= NB) return;
  int v = hist[lane*NB + b];
  int sc = v;
  #pragma unroll
  for (int d = 1; d < 64; d <<= 1){
    int t2 = __shfl_up(sc, d);
    if (lane >= d) sc += t2;
  }
  hist[lane*NB + b] = base[b] + sc - v;
}

__global__ __launch_bounds__(1024) void k_bfill(const int* ei, int E, const int* hist,
                                                u32* tmp, int NB){
  __shared__ int cur[512];
  for (int b = threadIdx.x; b < NB; b += 1024) cur[b] = hist[blockIdx.x*NB + b];
  __syncthreads();
  for (int e = blockIdx.x*1024 + threadIdx.x; e < E; e += BHB*1024){
    int s = ei[e], d = ei[E + e];
    int p = atomicAdd(&cur[((u32)d) >> SHB], 1);
    tmp[p] = ((u32)(d & (NPB-1)) << 24) | (u32)s;
  }
}

__global__ __launch_bounds__(256) void k_cfill(const u32* tmp, const int* base,
                                               int* coff, int* csr, int N){
  __shared__ int cnt[NPB], start[NPB];
  int b = blockIdx.x, t = threadIdx.x;
  int p0 = base[b], p1 = base[b + 1];
  cnt[t] = 0;
  __syncthreads();
  for (int i = p0 + t; i < p1; i += 256)
    atomicAdd(&cnt[tmp[i] >> 24], 1);
  __syncthreads();
  if (t == 0){
    int run = p0;
    for (int j = 0; j < NPB; j++){ start[j] = run; run += cnt[j]; }
  }
  __syncthreads();
  {
    int node = b*NPB + t;
    if (node < N) coff[node] = start[t];
    cnt[t] = 0;
  }
  __syncthreads();
  for (int i = p0 + t; i < p1; i += 256){
    u32 pr = tmp[i];
    int dj = pr >> 24;
    int r = atomicAdd(&cnt[dj], 1);
    csr[start[dj] + r] = (int)(pr & 0xFFFFFFu);
  }
}

// ---------------- layer-1 GEMM via MFMA + fused logits (full-row preload, packed stores) ----------------
__global__ __launch_bounds__(256) void k_mfma1A(const void* x, const u16* __restrict__ Wt,
    const void* a_s, const void* a_d,
    u16* __restrict__ out, u16* __restrict__ als, u16* __restrict__ ald,
    int n, const int* dflag)
{
  const int f32 = dflag[0];
  const int wave = threadIdx.x >> 6;
  const int lane = threadIdx.x & 63;
  const int l15 = lane & 15, q = lane >> 4;
  const int arow = blockIdx.x*64 + wave*16 + l15;
  const bool rok = arow < n;

  // preload whole row slice: 8 x float4 (f32) or 4 x short8 (bf16), all in flight
  short8 a4[4];
  #pragma unroll
  for (int kk = 0; kk < 4; kk++) a4[kk] = short8{0,0,0,0,0,0,0,0};
  if (rok){
    if (f32){
      const float* xp = (const float*)x + (size_t)arow*128;
      float4 xv[8];
      #pragma unroll
      for (int kk = 0; kk < 4; kk++){
        xv[2*kk]   = *(const float4*)(xp + kk*32 + q*8);
        xv[2*kk+1] = *(const float4*)(xp + kk*32 + q*8 + 4);
      }
      #pragma unroll
      for (int kk = 0; kk < 4; kk++){
        a4[kk][0]=(short)f2bf(xv[2*kk].x);   a4[kk][1]=(short)f2bf(xv[2*kk].y);
        a4[kk][2]=(short)f2bf(xv[2*kk].z);   a4[kk][3]=(short)f2bf(xv[2*kk].w);
        a4[kk][4]=(short)f2bf(xv[2*kk+1].x); a4[kk][5]=(short)f2bf(xv[2*kk+1].y);
        a4[kk][6]=(short)f2bf(xv[2*kk+1].z); a4[kk][7]=(short)f2bf(xv[2*kk+1].w);
      }
    } else {
      const u16* xp = (const u16*)x + (size_t)arow*128;
      #pragma unroll
      for (int kk = 0; kk < 4; kk++) a4[kk] = *(const short8*)(xp + kk*32 + q*8);
    }
  }

  f32x4 acc[8];
  #pragma unroll
  for (int t = 0; t < 8; t++) acc[t] = {0.f, 0.f, 0.f, 0.f};

  #pragma unroll
  for (int kk = 0; kk < 4; kk++){
    #pragma unroll
    for (int t = 0; t < 8; t++){
      short8 b = *(const short8*)(Wt + (size_t)(l15 + 16*t)*128 + kk*32 + q*8);
      acc[t] = __builtin_amdgcn_mfma_f32_16x16x32_bf16(a4[kk], b, acc[t], 0, 0, 0);
    }
  }

  // packed stores: pair even/odd l15 lanes via shfl (cols c,c+1 -> one u32)
  const int orow0 = blockIdx.x*64 + wave*16 + q*4;
  #pragma unroll
  for (int r = 0; r < 4; r++){
    int orow = orow0 + r;
    u32 po[8];
    #pragma unroll
    for (int t = 0; t < 8; t++){
      u32 bown = f2bf(acc[t][r]);
      u32 both = __shfl_xor(bown, 1);
      po[t] = bown | (both << 16);          // valid for even l15 lanes
    }
    if (orow < n && (l15 & 1) == 0){
      u32* op = (u32*)(out + (size_t)orow*128);
      #pragma unroll
      for (int t = 0; t < 8; t++) op[(l15 >> 1) + 8*t] = po[t];
    }
  }

  // fused logits
  float as_l[8], ad_l[8];
  #pragma unroll
  for (int t = 0; t < 8; t++){
    as_l[t] = gload(a_s, t*16 + l15, f32);
    ad_l[t] = gload(a_d, t*16 + l15, f32);
  }
  #pragma unroll
  for (int r = 0; r < 4; r++){
    float s[8], d[8];
    #pragma unroll
    for (int t = 0; t < 8; t++){
      s[t] = acc[t][r] * as_l[t];
      d[t] = acc[t][r] * ad_l[t];
    }
    #pragma unroll
    for (int st = 1; st < 16; st <<= 1){
      #pragma unroll
      for (int t = 0; t < 8; t++){
        s[t] += __shfl_xor(s[t], st);
        d[t] += __shfl_xor(d[t], st);
      }
    }
    int orow = orow0 + r;
    if (l15 == 0 && orow < n){
      short8 sv, dv;
      #pragma unroll
      for (int t = 0; t < 8; t++){
        sv[t] = (short)f2bf(s[t] * LOG2E);
        dv[t] = (short)f2bf(d[t] * LOG2E);
      }
      *(short8*)(als + (size_t)orow*8) = sv;
      *(short8*)(ald + (size_t)orow*8) = dv;
    }
  }
}

// ---------------- vector GEMM ----------------
template<int K,int M,int RT,int TPB,bool AFFINE,bool WBF16>
__global__ __launch_bounds__(TPB) void k_gemm(
    const u16* in, const void* Wg,
    const float* stat, const void* gam, const void* bet, float invn,
    u16* out, int n, const int* dflag)
{
  constexpr int CT = 4;
  constexpr int TC = M/CT;
  constexpr int TR = TPB/TC;
  constexpr int ROWS = TR*RT;
  static_assert(TPB % TC == 0, "");
  __shared__ __align__(16) u16 Wl[K*M];
  __shared__ float Il[ROWS*(K+1)];
  __shared__ float faL[AFFINE ? K : 1], fdL[AFFINE ? K : 1];

  const int f32 = dflag[0];
  if constexpr (AFFINE){
    for (int k = threadIdx.x; k < K; k += TPB){
      float m = stat[k]*invn;
      float vv = stat[128 + k]*invn - m*m;
      float a = gload(gam, k, f32) * rsqrtf(vv + 1e-5f);
      faL[k] = a;
      fdL[k] = gload(bet, k, f32) - m*a;
    }
    __syncthreads();
  }

  for (int i = threadIdx.x; i < K*M; i += TPB){
    if constexpr (WBF16) Wl[i] = ((const u16*)Wg)[i];
    else Wl[i] = f32 ? f2bf(((const float*)Wg)[i]) : ((const u16*)Wg)[i];
  }

  const int rowbase = blockIdx.x * ROWS;
  for (int i = threadIdx.x; i < ROWS*K; i += TPB){
    int rr = i / K, k = i - rr*K;
    int r = rowbase + rr;
    float v = 0.f;
    if (r < n){
      v = bf2f(in[(size_t)r*K + k]);
      if constexpr (AFFINE) v = fmaxf(fmaf(faL[k], v, fdL[k]), 0.f);
    }
    Il[rr*(K+1) + k] = v;
  }
  __syncthreads();

  const int tc = threadIdx.x % TC;
  const int tr = threadIdx.x / TC;
  float acc[RT][CT];
  #pragma unroll
  for (int j = 0; j < RT; j++)
    #pragma unroll
    for (int c = 0; c < CT; c++) acc[j][c] = 0.f;

  #pragma unroll 8
  for (int k = 0; k < K; k++){
    ushort4 u = *(const ushort4*)&Wl[k*M + tc*CT];
    float w0 = bf2f(u.x), w1 = bf2f(u.y), w2 = bf2f(u.z), w3 = bf2f(u.w);
    #pragma unroll
    for (int j = 0; j < RT; j++){
      float iv = Il[(tr + j*TR)*(K+1) + k];
      acc[j][0] = fmaf(iv, w0, acc[j][0]);
      acc[j][1] = fmaf(iv, w1, acc[j][1]);
      acc[j][2] = fmaf(iv, w2, acc[j][2]);
      acc[j][3] = fmaf(iv, w3, acc[j][3]);
    }
  }

  #pragma unroll
  for (int j = 0; j < RT; j++){
    int r = rowbase + tr + j*TR;
    if (r < n){
      ushort4 st;
      st.x = f2bf(acc[j][0]); st.y = f2bf(acc[j][1]);
      st.z = f2bf(acc[j][2]); st.w = f2bf(acc[j][3]);
      *(ushort4*)&out[(size_t)r*M + tc*CT] = st;
    }
  }
}

// ---------------- layer-1 GAT pull (role-split + software-pipelined weight phase) ----------------
template<int H,int C>
__global__ __launch_bounds__(256) void k_pullW(const u16* __restrict__ h,
    const u16* __restrict__ als, const u16* __restrict__ ald,
    const int* __restrict__ off, const int* __restrict__ csr, u16* __restrict__ out, int n)
{
  constexpr int F = H*C;
  constexpr int L = F/2;
  constexpr int LOGH = (H==8)?3:((H==4)?2:1);
  constexpr int EPG = 64 >> LOGH;
  int wid = blockIdx.x*4 + (threadIdx.x >> 6);
  if (wid >= n) return;
  int lane = threadIdx.x & 63;
  int uu = lane >> LOGH;
  int hh = lane & (H-1);
  int fl = (lane < L) ? lane : (L-1);
  int hd = (2*fl)/C;
  const u32* hw = (const u32*)h;

  float adw = bf2f(ald[(u32)wid*H + hh]);
  float wsw = exp2g(lrelu(bf2f(als[(u32)wid*H + hh]) + adw));
  float den_lane = (uu == 0) ? wsw : 0.f;

  float wsf = exp2g(lrelu(bf2f(als[(u32)wid*H + hd]) + bf2f(ald[(u32)wid*H + hd])));
  u32 vs = hw[(u32)wid*L + fl];
  float acc0 = wsf * bf2f((u16)vs);
  float acc1 = wsf * bf2f((u16)(vs >> 16));

  int e0 = off[wid], e1 = off[wid + 1];
  int su = 0; float bl = 0.f;
  if (e0 < e1){
    int rem = e1 - e0;
    su = csr[e0 + (uu < rem ? uu : 0)];
    bl = bf2f(als[(u32)su*H + hh]);
  }
  for (int e = e0; e < e1; e += EPG){
    int rem = e1 - e;
    int cur = su; float blc = bl;
    int en = e + EPG;
    if (en < e1){                               // prefetch next group
      int remn = e1 - en;
      su = csr[en + (uu < remn ? uu : 0)];
      bl = bf2f(als[(u32)su*H + hh]);
    }
    float w = exp2g(lrelu(blc + adw));
    if (uu >= rem) w = 0.f;
    den_lane += w;
    int cnt = rem < EPG ? rem : EPG;
    for (int jj = 0; jj < cnt; jj += 8){
      int sb[8]; float wb[8]; u32 vv[8];
      #pragma unroll
      for (int j = 0; j < 8; j++){
        int sl = ((jj + j) << LOGH) + hd;
        sb[j] = __shfl(cur, sl);
        wb[j] = __shfl(w,   sl);
      }
      #pragma unroll
      for (int j = 0; j < 8; j++) vv[j] = hw[(u32)sb[j]*L + fl];
      #pragma unroll
      for (int j = 0; j < 8; j++){
        acc0 = fmaf(wb[j], bf2f((u16)vv[j]), acc0);
        acc1 = fmaf(wb[j], bf2f((u16)(vv[j] >> 16)), acc1);
      }
    }
  }
  #pragma unroll
  for (int st = H; st < 64; st <<= 1) den_lane += __shfl_xor(den_lane, st);
  float den = __shfl(den_lane, hd);
  float r = 1.f/(den + 1e-16f);
  if (lane < L)
    ((u32*)out)[(u32)wid*L + fl] = (u32)f2bf(acc0*r) | ((u32)f2bf(acc1*r) << 16);
}

// ---------------- layers 2/3: logits + activated rows (u32 loads) ----------------
template<int H,int CIN>
__global__ __launch_bounds__(256) void k_alphaX(const u16* __restrict__ Cb,
    const float* stat, const void* gam, const void* bet, float invn,
    const float* vs, const float* vd,
    u16* act, u16* als, u16* ald, int n, const int* dflag)
{
  constexpr int L2 = CIN/2;
  const int f32 = dflag[0];
  __shared__ float faL[CIN], fdL[CIN];
  if (threadIdx.x < CIN){
    int k = threadIdx.x;
    float m = stat[k]*invn;
    float vv = stat[128 + k]*invn - m*m;
    float a = gload(gam, k, f32) * rsqrtf(vv + 1e-5f);
    faL[k] = a;
    fdL[k] = gload(bet, k, f32) - m*a;
  }
  __syncthreads();
  int idx = blockIdx.x*256 + threadIdx.x;
  if (idx >= n*H) return;
  int j = idx / H, h = idx - j*H;
  const u32* row32 = (const u32*)Cb + (size_t)j*L2;
  u32* act32 = (u32*)act + (size_t)j*L2;
  float s = 0.f, d = 0.f;
  #pragma unroll
  for (int k2 = 0; k2 < L2; k2++){
    u32 v = row32[k2];
    float v0 = fmaxf(fmaf(faL[2*k2],     bf2f((u16)v),         fdL[2*k2]),     0.f);
    float v1 = fmaxf(fmaf(faL[2*k2 + 1], bf2f((u16)(v >> 16)), fdL[2*k2 + 1]), 0.f);
    s = fmaf(v0, vs[h*CIN + 2*k2], s); s = fmaf(v1, vs[h*CIN + 2*k2 + 1], s);
    d = fmaf(v0, vd[h*CIN + 2*k2], d); d = fmaf(v1, vd[h*CIN + 2*k2 + 1], d);
    if (h == 0) act32[k2] = (u32)f2bf(v0) | ((u32)f2bf(v1) << 16);
  }
  als[idx] = f2bf(s * LOG2E); ald[idx] = f2bf(d * LOG2E);
}

// ---------------- layers 2/3: input-space pull (software-pipelined) ----------------
template<int H,int CIN>
__global__ __launch_bounds__(256) void k_pullX(const u16* __restrict__ act,
    const u16* __restrict__ als, const u16* __restrict__ ald,
    const int* __restrict__ off, const int* __restrict__ csr, u16* __restrict__ D, int n)
{
  constexpr int LX = H*CIN;
  constexpr int LOGH = (H==4)?2:1;
  constexpr int EPG = 64 >> LOGH;
  int wid = blockIdx.x*4 + (threadIdx.x >> 6);
  if (wid >= n) return;
  int lane = threadIdx.x & 63;
  int uu = lane >> LOGH;
  int hh = lane & (H-1);
  int fl = (lane < LX) ? lane : (LX-1);
  int hf = fl / CIN, k = fl - hf*CIN;

  float adw = bf2f(ald[(u32)wid*H + hh]);
  float wsw = exp2g(lrelu(bf2f(als[(u32)wid*H + hh]) + adw));
  float den_lane = (uu == 0) ? wsw : 0.f;

  float wsf = exp2g(lrelu(bf2f(als[(u32)wid*H + hf]) + bf2f(ald[(u32)wid*H + hf])));
  float acc = wsf * bf2f(act[(u32)wid*CIN + k]);

  int e0 = off[wid], e1 = off[wid + 1];
  int su = 0; float bl = 0.f;
  if (e0 < e1){
    int rem = e1 - e0;
    su = csr[e0 + (uu < rem ? uu : 0)];
    bl = bf2f(als[(u32)su*H + hh]);
  }
  for (int e = e0; e < e1; e += EPG){
    int rem = e1 - e;
    int cur = su; float blc = bl;
    int en = e + EPG;
    if (en < e1){
      int remn = e1 - en;
      su = csr[en + (uu < remn ? uu : 0)];
      bl = bf2f(als[(u32)su*H + hh]);
    }
    float w = exp2g(lrelu(blc + adw));
    if (uu >= rem) w = 0.f;
    den_lane += w;
    int cnt = rem < EPG ? rem : EPG;
    for (int jj = 0; jj < cnt; jj += 8){
      int sb[8]; float wb[8]; u16 vv[8];
      #pragma unroll
      for (int j = 0; j < 8; j++){
        int sl = ((jj + j) << LOGH) + hf;
        sb[j] = __shfl(cur, sl);
        wb[j] = __shfl(w,   sl);
      }
      #pragma unroll
      for (int j = 0; j < 8; j++) vv[j] = act[(u32)sb[j]*CIN + k];
      #pragma unroll
      for (int j = 0; j < 8; j++) acc = fmaf(wb[j], bf2f(vv[j]), acc);
    }
  }
  #pragma unroll
  for (int st = H; st < 64; st <<= 1) den_lane += __shfl_xor(den_lane, st);
  float den = __shfl(den_lane, hf);
  if (lane < LX)
    D[(u32)wid*LX + fl] = f2bf(acc / (den + 1e-16f));
}

// ---------------- fused column stats: partials + last-block fold ----------------
template<int F,int TPB>
__global__ __launch_bounds__(TPB) void k_statAB(const u16* __restrict__ x, int n,
    float* __restrict__ part, float* __restrict__ outS, int* __restrict__ cnt)
{
  constexpr int L = F/2;
  constexpr int RPB = TPB/L;
  static_assert(TPB % L == 0, "");
  int c = threadIdx.x % L;
  int tr = threadIdx.x / L;
  const u32* xw = (const u32*)x;
  int chunk = (n + (int)gridDim.x - 1)/(int)gridDim.x;
  int r0 = blockIdx.x*chunk;
  int r1 = r0 + chunk; if (r1 > n) r1 = n;
  float a0=0.f, a1=0.f, b0=0.f, b1=0.f;
  int r = r0 + tr;
  for (; r + 3*RPB < r1; r += 4*RPB){
    u32 v0 = xw[(size_t)r*L + c];
    u32 v1 = xw[(size_t)(r + RPB)*L + c];
    u32 v2 = xw[(size_t)(r + 2*RPB)*L + c];
    u32 v3 = xw[(size_t)(r + 3*RPB)*L + c];
    float f0 = bf2f((u16)v0), f1 = bf2f((u16)(v0 >> 16));
    float f2 = bf2f((u16)v1), f3 = bf2f((u16)(v1 >> 16));
    float f4 = bf2f((u16)v2), f5 = bf2f((u16)(v2 >> 16));
    float f6 = bf2f((u16)v3), f7 = bf2f((u16)(v3 >> 16));
    a0 += (f0 + f2) + (f4 + f6);
    a1 += (f1 + f3) + (f5 + f7);
    b0 += (f0*f0 + f2*f2) + (f4*f4 + f6*f6);
    b1 += (f1*f1 + f3*f3) + (f5*f5 + f7*f7);
  }
  for (; r < r1; r += RPB){
    u32 v = xw[(size_t)r*L + c];
    float f0 = bf2f((u16)v), f1 = bf2f((u16)(v >> 16));
    a0 += f0; b0 = fmaf(f0, f0, b0);
    a1 += f1; b1 = fmaf(f1, f1, b1);
  }
  __shared__ float l0[TPB], l1[TPB], l2[TPB], l3[TPB];
  l0[threadIdx.x] = a0; l1[threadIdx.x] = a1;
  l2[threadIdx.x] = b0; l3[threadIdx.x] = b1;
  __syncthreads();
  for (int t2 = threadIdx.x; t2 < 256; t2 += TPB){
    int col = t2 & 127;
    float s = 0.f;
    if (col < F){
      int cc = col >> 1, par = col & 1;
      const float* base = (t2 >= 128) ? (par ? l3 : l2) : (par ? l1 : l0);
      #pragma unroll 4
      for (int j = 0; j < RPB; j++) s += base[j*L + cc];
    }
    part[(size_t)blockIdx.x*256 + t2] = s;
  }
  __threadfence();
  __shared__ int lastf;
  if (threadIdx.x == 0) lastf = (atomicAdd(cnt, 1) == (int)gridDim.x - 1) ? 1 : 0;
  __syncthreads();
  if (lastf){
    __threadfence();
    for (int t2 = threadIdx.x; t2 < 256; t2 += TPB){
      float s = 0.f;
      int b = 0;
      for (; b + 3 < PST; b += 4)
        s += (part[(size_t)b*256 + t2] + part[(size_t)(b+1)*256 + t2])
           + (part[(size_t)(b+2)*256 + t2] + part[(size_t)(b+3)*256 + t2]);
      for (; b < PST; b++) s += part[(size_t)b*256 + t2];
      outS[t2] = s;
    }
  }
}

// ---------------- pool per graph + classifier ----------------
__global__ __launch_bounds__(256) void k_pool(const u16* B, const int* batch, int n,
    const float* stat, const void* g3, const void* be3, float invn,
    const void* Wo, const void* bo, void* outp, const int* dflag)
{
  const int f32 = dflag[0];
  __shared__ float fa[64], fd[64];
  if (threadIdx.x < 64){
    int k = threadIdx.x;
    float m = stat[k]*invn;
    float v = stat[128 + k]*invn - m*m;
    float a = gload(g3, k, f32) * rsqrtf(v + 1e-5f);
    fa[k] = a;
    fd[k] = gload(be3, k, f32) - m*a;
  }
  __syncthreads();

  int g = blockIdx.x;
  int lane = threadIdx.x & 63, wv = threadIdx.x >> 6;
  int s, e;
  { int l = 0, h = n; while (l < h){ int m = (l+h)>>1; if (batch[m] <  g) l = m+1; else h = m; } s = l; }
  { int l = s, h = n; while (l < h){ int m = (l+h)>>1; if (batch[m] <= g) l = m+1; else h = m; } e = l; }
  float a = fa[lane], d = fd[lane], acc = 0.f;
  for (int r = s + wv; r < e; r += 4)
    acc += fmaxf(fmaf(a, bf2f(B[(size_t)r*64 + lane]), d), 0.f);
  __shared__ float pl[4][64];
  pl[wv][lane] = acc;
  __syncthreads();
  if (wv == 0){
    float cnt = (e > s) ? (float)(e - s) : 1.f;
    pl[0][lane] = (pl[0][lane] + pl[1][lane] + pl[2][lane] + pl[3][lane]) / cnt;
  }
  __syncthreads();
  if (threadIdx.x < 10){
    int lo = threadIdx.x;
    float o = gload(bo, lo, f32);
    for (int l2 = 0; l2 < 64; l2++) o = fmaf(pl[0][l2], gload(Wo, l2*10 + lo, f32), o);
    if (f32) ((float*)outp)[g*10 + lo] = o;
    else     ((u16*) outp)[g*10 + lo] = f2bf(o);
  }
}

// ---------------- launch ----------------
extern "C" void kernel_launch(void* const* d_in, const int* in_sizes, int n_in,
                              void* d_out, int out_size, void* d_ws, size_t ws_size,
                              hipStream_t stream)
{
  const void* x   = d_in[0];
  const int* ei   = (const int*)d_in[1];
  const int* batch= (const int*)d_in[2];
  const void* W1  = d_in[3];
  const void* as1 = d_in[4];
  const void* ad1 = d_in[5];
  const void* g1  = d_in[7];
  const void* be1 = d_in[8];
  const void* Wl1 = d_in[9];
  const void* gl1 = d_in[11];
  const void* bel1= d_in[12];
  const void* W2  = d_in[13];
  const void* as2 = d_in[14];
  const void* ad2 = d_in[15];
  const void* g2  = d_in[17];
  const void* be2 = d_in[18];
  const void* Wl2 = d_in[19];
  const void* gl2 = d_in[21];
  const void* bel2= d_in[22];
  const void* W3  = d_in[23];
  const void* as3 = d_in[24];
  const void* ad3 = d_in[25];
  const void* g3  = d_in[27];
  const void* be3 = d_in[28];
  const void* Wo  = d_in[29];
  const void* bo  = d_in[30];
  (void)n_in; (void)ws_size;

  const int N = in_sizes[2];
  const int E = in_sizes[1] / 2;
  const int G = out_size / 10;
  const int NB = (N + NPB - 1) >> SHB;

  char* w = (char*)d_ws;
  size_t off = 0;
  auto alloc = [&](size_t bytes)->void*{
    size_t o = off; off += (bytes + 255) & ~(size_t)255; return (void*)(w + o);
  };
  int*   dflag= (int*)alloc(4);
  int*   cnts = (int*)alloc(8*4);
  int*   coff = (int*)alloc((size_t)(N+1)*4);
  int*   csr  = (int*)alloc((size_t)E*4);
  int*   bbase= (int*)alloc((size_t)(NB+1)*4);
  int*   btot = (int*)alloc((size_t)NB*4);
  int*   hist = (int*)alloc((size_t)BHB*NB*4);
  float* stS  = (float*)alloc(1280*4);
  float* part = (float*)alloc((size_t)PST*256*4);
  float* prepF= (float*)alloc(256*4);
  u16*   Wt   = (u16*)alloc(128*128*2);
  u16*   Wbd2 = (u16*)alloc(64*96*2);
  u16*   Wbd3 = (u16*)alloc(48*64*2);
  u16*   als  = (u16*)alloc((size_t)N*8*2);
  u16*   ald  = (u16*)alloc((size_t)N*8*2);
  u16*   Cb   = (u16*)alloc((size_t)N*24*2);
  u16*   A    = (u16*)alloc((size_t)N*128*2);
  u16*   B    = (u16*)alloc((size_t)N*128*2);
  u32*   tmp  = (u32*)A;
  u16*   D    = A;
  u16*   act  = A + (size_t)N*64;

  const float invN = 1.f/(float)N;
  const int nbw = (NB + 3)/4;

  k_prep<<<18, 256, 0, stream>>>(x, W1, W2, as2, ad2, W3, as3, ad3,
                                 dflag, Wt, Wbd2, Wbd3, prepF, cnts);

  k_bhist<<<BHB, 1024, 0, stream>>>(ei, E, hist, NB);
  k_btotW<<<nbw, 256, 0, stream>>>(hist, btot, NB);
  k_bscan<<<1, 512, 0, stream>>>(btot, bbase, coff, NB, N);
  k_bcurW<<<nbw, 256, 0, stream>>>(hist, bbase, NB);
  k_bfill<<<BHB, 1024, 0, stream>>>(ei, E, hist, tmp, NB);
  k_cfill<<<NB, 256, 0, stream>>>(tmp, bbase, coff, csr, N);

  k_mfma1A<<<(N+63)/64, 256, 0, stream>>>(x, Wt, as1, ad1, A, als, ald, N, dflag);
  k_pullW<8,16><<<(N+3)/4, 256, 0, stream>>>(A, als, ald, coff, csr, B, N);
  k_statAB<128,256><<<PST, 256, 0, stream>>>(B, N, part, stS + 0, cnts + 0);

  k_gemm<128,16,1,256,true,false><<<(N+63)/64, 256, 0, stream>>>(
      B, Wl1, stS + 0, g1, be1, invN, Cb, N, dflag);
  k_statAB<16,256><<<PST, 256, 0, stream>>>(Cb, N, part, stS + 256, cnts + 1);

  k_alphaX<4,16><<<(N*4+255)/256, 256, 0, stream>>>(
      Cb, stS + 256, gl1, bel1, invN, prepF + 0, prepF + 64, act, als, ald, N, dflag);
  k_pullX<4,16><<<(N+3)/4, 256, 0, stream>>>(act, als, ald, coff, csr, D, N);
  k_gemm<64,96,2,192,false,true><<<(N+15)/16, 192, 0, stream>>>(
      D, Wbd2, nullptr, nullptr, nullptr, invN, B, N, dflag);
  k_statAB<96,192><<<PST, 192, 0, stream>>>(B, N, part, stS + 512, cnts + 2);

  k_gemm<96,24,2,192,true,false><<<(N+63)/64, 192, 0, stream>>>(
      B, Wl2, stS + 512, g2, be2, invN, Cb, N, dflag);
  k_statAB<24,192><<<PST, 192, 0, stream>>>(Cb, N, part, stS + 768, cnts + 3);

  k_alphaX<2,24><<<(N*2+255)/256, 256, 0, stream>>>(
      Cb, stS + 768, gl2, bel2, invN, prepF + 128, prepF + 176, act, als, ald, N, dflag);
  k_pullX<2,24><<<(N+3)/4, 256, 0, stream>>>(act, als, ald, coff, csr, D, N);
  k_gemm<48,64,2,256,false,true><<<(N+31)/32, 256, 0, stream>>>(
      D, Wbd3, nullptr, nullptr, nullptr, invN, B, N, dflag);
  k_statAB<64,256><<<PST, 256, 0, stream>>>(B, N, part, stS + 1024, cnts + 4);

  k_pool<<<G, 256, 0, stream>>>(B, batch, N, stS + 1024, g3, be3, invN, Wo, bo, d_out, dflag);
}

// Round 16
// 694.952 us; speedup vs baseline: 1.1309x; 1.1309x over previous
//
#include <hip/hip_runtime.h>

typedef unsigned short u16;
typedef unsigned int   u32;
typedef unsigned long long u64;
typedef __attribute__((ext_vector_type(8))) short short8;
typedef __attribute__((ext_vector_type(4))) float f32x4;

#define DEVI __device__ __forceinline__

#define NPB 256      // nodes per coarse bucket
#define SHB 8        // log2(NPB)
#define BHB 64       // blocks for bucket hist/fill passes
#define PST 256      // stat phase-A blocks
#define LOG2E 1.44269504088896340736f

DEVI float bf2f(u16 u){ union{u32 i; float f;} x; x.i = ((u32)u)<<16; return x.f; }
DEVI u16 f2bf(float f){ union{float f; u32 i;} x; x.f = f;
  u32 r = (x.i + 0x7FFFu + ((x.i>>16)&1u))>>16; return (u16)r; }
DEVI float lrelu(float x){ return x > 0.f ? x : 0.2f*x; }
DEVI float exp2g(float x){ return __builtin_amdgcn_exp2f(x); }
DEVI float gload(const void* p, size_t i, int f32){
  return f32 ? ((const float*)p)[i] : bf2f(((const u16*)p)[i]);
}

// ---------------- merged prep: dtype detect + W1^T + block-diag W2/W3 + logit vecs + counters ----------------
__global__ __launch_bounds__(256) void k_prep(const void* x, const void* W1,
    const void* W2, const void* as2, const void* ad2,
    const void* W3, const void* as3, const void* ad3,
    int* dflag, u16* Wt, u16* Wbd2, u16* Wbd3, float* prepF, int* cnts)
{
  __shared__ int sf32;
  if (threadIdx.x == 0){
    const u16* p = (const u16*)x;
    int hits = 0;
    for (int j = 0; j < 512; j++){
      u16 e = (p[j] >> 7) & 0xFF;
      if (e >= 0xC0) hits++;
    }
    sf32 = hits ? 1 : 0;
    if (blockIdx.x == 0) *dflag = sf32;
  }
  __syncthreads();
  const int f32 = sf32;
  int b = blockIdx.x, t = threadIdx.x;
  if (b < 16){
    for (int i = b*256 + t; i < 128*128; i += 16*256){
      int k = i >> 7, nn = i & 127;
      Wt[nn*128 + k] = f2bf(gload(W1, i, f32));
    }
  } else if (b == 16){
    for (int i = t; i < 64*96; i += 256){
      int r = i/96, m = i - r*96;
      int h = r >> 4, k = r & 15;
      float v = ((m/24) == h) ? gload(W2, k*96 + m, f32) : 0.f;
      Wbd2[i] = f2bf(v);
    }
    if (t < 64){
      int h = t >> 4, k = t & 15;
      float s = 0.f, d = 0.f;
      for (int c = 0; c < 24; c++){
        float w = gload(W2, k*96 + h*24 + c, f32);
        s = fmaf(w, gload(as2, h*24 + c, f32), s);
        d = fmaf(w, gload(ad2, h*24 + c, f32), d);
      }
      prepF[t] = s; prepF[64 + t] = d;
    }
  } else {
    for (int i = t; i < 48*64; i += 256){
      int r = i >> 6, m = i & 63;
      int h = r/24, k = r - h*24;
      float v = ((m >> 5) == h) ? gload(W3, k*64 + m, f32) : 0.f;
      Wbd3[i] = f2bf(v);
    }
    if (t < 48){
      int h = t/24, k = t - h*24;
      float s = 0.f, d = 0.f;
      for (int c = 0; c < 32; c++){
        float w = gload(W3, k*64 + h*32 + c, f32);
        s = fmaf(w, gload(as3, h*32 + c, f32), s);
        d = fmaf(w, gload(ad3, h*32 + c, f32), d);
      }
      prepF[128 + t] = s; prepF[176 + t] = d;
    }
    if (t >= 64 && t < 72) cnts[t - 64] = 0;
  }
}

// ---------------- CSR build ----------------
__global__ __launch_bounds__(1024) void k_bhist(const int* ei, int E, int* hist, int NB){
  __shared__ int lh[512];
  for (int b = threadIdx.x; b < NB; b += 1024) lh[b] = 0;
  __syncthreads();
  for (int e = blockIdx.x*1024 + threadIdx.x; e < E; e += BHB*1024)
    atomicAdd(&lh[((u32)ei[E + e]) >> SHB], 1);
  __syncthreads();
  for (int b = threadIdx.x; b < NB; b += 1024) hist[blockIdx.x*NB + b] = lh[b];
}

__global__ __launch_bounds__(256) void k_btotW(const int* hist, int* tot, int NB){
  int wv = threadIdx.x >> 6, lane = threadIdx.x & 63;
  int b = blockIdx.x*4 + wv;
  if (b >= NB) return;
  int v = hist[lane*NB + b];
  #pragma unroll
  for (int st = 1; st < 64; st <<= 1) v += __shfl_xor(v, st);
  if (lane == 0) tot[b] = v;
}

__global__ __launch_bounds__(512) void k_bscan(const int* tot, int* base, int* coff, int NB, int N){
  __shared__ int l[512];
  int t = threadIdx.x;
  int v = (t < NB) ? tot[t] : 0;
  l[t] = v; __syncthreads();
  for (int st = 1; st < 512; st <<= 1){
    int a = (t >= st) ? l[t - st] : 0;
    __syncthreads();
    l[t] += a;
    __syncthreads();
  }
  if (t < NB) base[t] = l[t] - v;
  if (t == 511){ base[NB] = l[511]; coff[N] = l[511]; }
}

__global__ __launch_bounds__(256) void k_bcurW(int* hist, const int* base, int NB){
  int wv = threadIdx.x >> 6, lane = threadIdx.x & 63;
  int b = blockIdx.x*4 + wv;
  if (b >= NB) return;
  int v = hist[lane*NB + b];
  int sc = v;
  #pragma unroll
  for (int d = 1; d < 64; d <<= 1){
    int t2 = __shfl_up(sc, d);
    if (lane >= d) sc += t2;
  }
  hist[lane*NB + b] = base[b] + sc - v;
}

__global__ __launch_bounds__(1024) void k_bfill(const int* ei, int E, const int* hist,
                                                u32* tmp, int NB){
  __shared__ int cur[512];
  for (int b = threadIdx.x; b < NB; b += 1024) cur[b] = hist[blockIdx.x*NB + b];
  __syncthreads();
  for (int e = blockIdx.x*1024 + threadIdx.x; e < E; e += BHB*1024){
    int s = ei[e], d = ei[E + e];
    int p = atomicAdd(&cur[((u32)d) >> SHB], 1);
    tmp[p] = ((u32)(d & (NPB-1)) << 24) | (u32)s;
  }
}

__global__ __launch_bounds__(256) void k_cfill(const u32* tmp, const int* base,
                                               int* coff, int* csr, int N){
  __shared__ int cnt[NPB], start[NPB];
  int b = blockIdx.x, t = threadIdx.x;
  int p0 = base[b], p1 = base[b + 1];
  cnt[t] = 0;
  __syncthreads();
  for (int i = p0 + t; i < p1; i += 256)
    atomicAdd(&cnt[tmp[i] >> 24], 1);
  __syncthreads();
  if (t == 0){
    int run = p0;
    for (int j = 0; j < NPB; j++){ start[j] = run; run += cnt[j]; }
  }
  __syncthreads();
  {
    int node = b*NPB + t;
    if (node < N) coff[node] = start[t];
    cnt[t] = 0;
  }
  __syncthreads();
  for (int i = p0 + t; i < p1; i += 256){
    u32 pr = tmp[i];
    int dj = pr >> 24;
    int r = atomicAdd(&cnt[dj], 1);
    csr[start[dj] + r] = (int)(pr & 0xFFFFFFu);
  }
}

// ---------------- layer-1 GEMM via MFMA + fused attention logits ----------------
__global__ __launch_bounds__(256) void k_mfma1A(const void* x, const u16* __restrict__ Wt,
    const void* a_s, const void* a_d,
    u16* __restrict__ out, u16* __restrict__ als, u16* __restrict__ ald,
    int n, const int* dflag)
{
  const int f32 = dflag[0];
  const int wave = threadIdx.x >> 6;
  const int lane = threadIdx.x & 63;
  const int l15 = lane & 15, q = lane >> 4;
  const int arow = blockIdx.x*64 + wave*16 + l15;
  const bool rok = arow < n;

  f32x4 acc[8];
  #pragma unroll
  for (int t = 0; t < 8; t++) acc[t] = {0.f, 0.f, 0.f, 0.f};

  #pragma unroll
  for (int kk = 0; kk < 4; kk++){
    short8 a = {0,0,0,0,0,0,0,0};
    if (rok){
      const int ko = kk*32 + q*8;
      if (f32){
        const float* xp = (const float*)x + (size_t)arow*128 + ko;
        float4 v0 = *(const float4*)xp;
        float4 v1 = *(const float4*)(xp + 4);
        a[0]=(short)f2bf(v0.x); a[1]=(short)f2bf(v0.y); a[2]=(short)f2bf(v0.z); a[3]=(short)f2bf(v0.w);
        a[4]=(short)f2bf(v1.x); a[5]=(short)f2bf(v1.y); a[6]=(short)f2bf(v1.z); a[7]=(short)f2bf(v1.w);
      } else {
        a = *(const short8*)((const u16*)x + (size_t)arow*128 + ko);
      }
    }
    #pragma unroll
    for (int t = 0; t < 8; t++){
      short8 b = *(const short8*)(Wt + (size_t)(l15 + 16*t)*128 + kk*32 + q*8);
      acc[t] = __builtin_amdgcn_mfma_f32_16x16x32_bf16(a, b, acc[t], 0, 0, 0);
    }
  }

  const int orow0 = blockIdx.x*64 + wave*16 + q*4;
  #pragma unroll
  for (int r = 0; r < 4; r++){
    int orow = orow0 + r;
    if (orow < n){
      #pragma unroll
      for (int t = 0; t < 8; t++)
        out[(size_t)orow*128 + l15 + 16*t] = f2bf(acc[t][r]);
    }
  }

  float as_l[8], ad_l[8];
  #pragma unroll
  for (int t = 0; t < 8; t++){
    as_l[t] = gload(a_s, t*16 + l15, f32);
    ad_l[t] = gload(a_d, t*16 + l15, f32);
  }
  #pragma unroll
  for (int r = 0; r < 4; r++){
    float s[8], d[8];
    #pragma unroll
    for (int t = 0; t < 8; t++){
      s[t] = acc[t][r] * as_l[t];
      d[t] = acc[t][r] * ad_l[t];
    }
    #pragma unroll
    for (int st = 1; st < 16; st <<= 1){
      #pragma unroll
      for (int t = 0; t < 8; t++){
        s[t] += __shfl_xor(s[t], st);
        d[t] += __shfl_xor(d[t], st);
      }
    }
    int orow = orow0 + r;
    if (l15 == 0 && orow < n){
      short8 sv, dv;
      #pragma unroll
      for (int t = 0; t < 8; t++){
        sv[t] = (short)f2bf(s[t] * LOG2E);
        dv[t] = (short)f2bf(d[t] * LOG2E);
      }
      *(short8*)(als + (size_t)orow*8) = sv;
      *(short8*)(ald + (size_t)orow*8) = dv;
    }
  }
}

// ---------------- vector GEMM ----------------
template<int K,int M,int RT,int TPB,bool AFFINE,bool WBF16>
__global__ __launch_bounds__(TPB) void k_gemm(
    const u16* in, const void* Wg,
    const float* stat, const void* gam, const void* bet, float invn,
    u16* out, int n, const int* dflag)
{
  constexpr int CT = 4;
  constexpr int TC = M/CT;
  constexpr int TR = TPB/TC;
  constexpr int ROWS = TR*RT;
  static_assert(TPB % TC == 0, "");
  __shared__ __align__(16) u16 Wl[K*M];
  __shared__ float Il[ROWS*(K+1)];
  __shared__ float faL[AFFINE ? K : 1], fdL[AFFINE ? K : 1];

  const int f32 = dflag[0];
  if constexpr (AFFINE){
    for (int k = threadIdx.x; k < K; k += TPB){
      float m = stat[k]*invn;
      float vv = stat[128 + k]*invn - m*m;
      float a = gload(gam, k, f32) * rsqrtf(vv + 1e-5f);
      faL[k] = a;
      fdL[k] = gload(bet, k, f32) - m*a;
    }
    __syncthreads();
  }

  for (int i = threadIdx.x; i < K*M; i += TPB){
    if constexpr (WBF16) Wl[i] = ((const u16*)Wg)[i];
    else Wl[i] = f32 ? f2bf(((const float*)Wg)[i]) : ((const u16*)Wg)[i];
  }

  const int rowbase = blockIdx.x * ROWS;
  for (int i = threadIdx.x; i < ROWS*K; i += TPB){
    int rr = i / K, k = i - rr*K;
    int r = rowbase + rr;
    float v = 0.f;
    if (r < n){
      v = bf2f(in[(size_t)r*K + k]);
      if constexpr (AFFINE) v = fmaxf(fmaf(faL[k], v, fdL[k]), 0.f);
    }
    Il[rr*(K+1) + k] = v;
  }
  __syncthreads();

  const int tc = threadIdx.x % TC;
  const int tr = threadIdx.x / TC;
  float acc[RT][CT];
  #pragma unroll
  for (int j = 0; j < RT; j++)
    #pragma unroll
    for (int c = 0; c < CT; c++) acc[j][c] = 0.f;

  #pragma unroll 8
  for (int k = 0; k < K; k++){
    ushort4 u = *(const ushort4*)&Wl[k*M + tc*CT];
    float w0 = bf2f(u.x), w1 = bf2f(u.y), w2 = bf2f(u.z), w3 = bf2f(u.w);
    #pragma unroll
    for (int j = 0; j < RT; j++){
      float iv = Il[(tr + j*TR)*(K+1) + k];
      acc[j][0] = fmaf(iv, w0, acc[j][0]);
      acc[j][1] = fmaf(iv, w1, acc[j][1]);
      acc[j][2] = fmaf(iv, w2, acc[j][2]);
      acc[j][3] = fmaf(iv, w3, acc[j][3]);
    }
  }

  #pragma unroll
  for (int j = 0; j < RT; j++){
    int r = rowbase + tr + j*TR;
    if (r < n){
      ushort4 st;
      st.x = f2bf(acc[j][0]); st.y = f2bf(acc[j][1]);
      st.z = f2bf(acc[j][2]); st.w = f2bf(acc[j][3]);
      *(ushort4*)&out[(size_t)r*M + tc*CT] = st;
    }
  }
}

// ---------------- layer-1 GAT pull (wave role-split) ----------------
template<int H,int C>
__global__ __launch_bounds__(256) void k_pullW(const u16* __restrict__ h,
    const u16* __restrict__ als, const u16* __restrict__ ald,
    const int* __restrict__ off, const int* __restrict__ csr, u16* __restrict__ out, int n)
{
  constexpr int F = H*C;
  constexpr int L = F/2;
  constexpr int LOGH = (H==8)?3:((H==4)?2:1);
  constexpr int EPG = 64 >> LOGH;
  int wid = blockIdx.x*4 + (threadIdx.x >> 6);
  if (wid >= n) return;
  int lane = threadIdx.x & 63;
  int uu = lane >> LOGH;
  int hh = lane & (H-1);
  int fl = (lane < L) ? lane : (L-1);
  int hd = (2*fl)/C;
  const u32* hw = (const u32*)h;

  float adw = bf2f(ald[(u32)wid*H + hh]);
  float wsw = exp2g(lrelu(bf2f(als[(u32)wid*H + hh]) + adw));
  float den_lane = (uu == 0) ? wsw : 0.f;

  float wsf = exp2g(lrelu(bf2f(als[(u32)wid*H + hd]) + bf2f(ald[(u32)wid*H + hd])));
  u32 vs = hw[(u32)wid*L + fl];
  float acc0 = wsf * bf2f((u16)vs);
  float acc1 = wsf * bf2f((u16)(vs >> 16));

  int e0 = off[wid], e1 = off[wid + 1];
  for (int e = e0; e < e1; e += EPG){
    int rem = e1 - e;
    int su = csr[e + (uu < rem ? uu : 0)];
    float w = exp2g(lrelu(bf2f(als[(u32)su*H + hh]) + adw));
    if (uu >= rem) w = 0.f;
    den_lane += w;
    int cnt = rem < EPG ? rem : EPG;
    for (int jj = 0; jj < cnt; jj += 8){
      int sb[8]; float wb[8]; u32 vv[8];
      #pragma unroll
      for (int j = 0; j < 8; j++){
        int sl = ((jj + j) << LOGH) + hd;
        sb[j] = __shfl(su, sl);
        wb[j] = __shfl(w,  sl);
      }
      #pragma unroll
      for (int j = 0; j < 8; j++) vv[j] = hw[(u32)sb[j]*L + fl];
      #pragma unroll
      for (int j = 0; j < 8; j++){
        acc0 = fmaf(wb[j], bf2f((u16)vv[j]), acc0);
        acc1 = fmaf(wb[j], bf2f((u16)(vv[j] >> 16)), acc1);
      }
    }
  }
  #pragma unroll
  for (int st = H; st < 64; st <<= 1) den_lane += __shfl_xor(den_lane, st);
  float den = __shfl(den_lane, hd);
  float r = 1.f/(den + 1e-16f);
  if (lane < L)
    ((u32*)out)[(u32)wid*L + fl] = (u32)f2bf(acc0*r) | ((u32)f2bf(acc1*r) << 16);
}

// ---------------- layers 2/3: logits + activated rows (u32 loads) ----------------
template<int H,int CIN>
__global__ __launch_bounds__(256) void k_alphaX(const u16* __restrict__ Cb,
    const float* stat, const void* gam, const void* bet, float invn,
    const float* vs, const float* vd,
    u16* act, u16* als, u16* ald, int n, const int* dflag)
{
  constexpr int L2 = CIN/2;
  const int f32 = dflag[0];
  __shared__ float faL[CIN], fdL[CIN];
  if (threadIdx.x < CIN){
    int k = threadIdx.x;
    float m = stat[k]*invn;
    float vv = stat[128 + k]*invn - m*m;
    float a = gload(gam, k, f32) * rsqrtf(vv + 1e-5f);
    faL[k] = a;
    fdL[k] = gload(bet, k, f32) - m*a;
  }
  __syncthreads();
  int idx = blockIdx.x*256 + threadIdx.x;
  if (idx >= n*H) return;
  int j = idx / H, h = idx - j*H;
  const u32* row32 = (const u32*)Cb + (size_t)j*L2;
  u32* act32 = (u32*)act + (size_t)j*L2;
  float s = 0.f, d = 0.f;
  #pragma unroll
  for (int k2 = 0; k2 < L2; k2++){
    u32 v = row32[k2];
    float v0 = fmaxf(fmaf(faL[2*k2],     bf2f((u16)v),         fdL[2*k2]),     0.f);
    float v1 = fmaxf(fmaf(faL[2*k2 + 1], bf2f((u16)(v >> 16)), fdL[2*k2 + 1]), 0.f);
    s = fmaf(v0, vs[h*CIN + 2*k2], s); s = fmaf(v1, vs[h*CIN + 2*k2 + 1], s);
    d = fmaf(v0, vd[h*CIN + 2*k2], d); d = fmaf(v1, vd[h*CIN + 2*k2 + 1], d);
    if (h == 0) act32[k2] = (u32)f2bf(v0) | ((u32)f2bf(v1) << 16);
  }
  als[idx] = f2bf(s * LOG2E); ald[idx] = f2bf(d * LOG2E);
}

// ---------------- layers 2/3: input-space pull -> per-head aggregates D[N, H*CIN] ----------------
template<int H,int CIN>
__global__ __launch_bounds__(256) void k_pullX(const u16* __restrict__ act,
    const u16* __restrict__ als, const u16* __restrict__ ald,
    const int* __restrict__ off, const int* __restrict__ csr, u16* __restrict__ D, int n)
{
  constexpr int LX = H*CIN;
  constexpr int LOGH = (H==4)?2:1;
  constexpr int EPG = 64 >> LOGH;
  int wid = blockIdx.x*4 + (threadIdx.x >> 6);
  if (wid >= n) return;
  int lane = threadIdx.x & 63;
  int uu = lane >> LOGH;
  int hh = lane & (H-1);
  int fl = (lane < LX) ? lane : (LX-1);
  int hf = fl / CIN, k = fl - hf*CIN;

  float adw = bf2f(ald[(u32)wid*H + hh]);
  float wsw = exp2g(lrelu(bf2f(als[(u32)wid*H + hh]) + adw));
  float den_lane = (uu == 0) ? wsw : 0.f;

  float wsf = exp2g(lrelu(bf2f(als[(u32)wid*H + hf]) + bf2f(ald[(u32)wid*H + hf])));
  float acc = wsf * bf2f(act[(u32)wid*CIN + k]);

  int e0 = off[wid], e1 = off[wid + 1];
  for (int e = e0; e < e1; e += EPG){
    int rem = e1 - e;
    int su = csr[e + (uu < rem ? uu : 0)];
    float w = exp2g(lrelu(bf2f(als[(u32)su*H + hh]) + adw));
    if (uu >= rem) w = 0.f;
    den_lane += w;
    int cnt = rem < EPG ? rem : EPG;
    for (int jj = 0; jj < cnt; jj += 8){
      int sb[8]; float wb[8]; u16 vv[8];
      #pragma unroll
      for (int j = 0; j < 8; j++){
        int sl = ((jj + j) << LOGH) + hf;
        sb[j] = __shfl(su, sl);
        wb[j] = __shfl(w,  sl);
      }
      #pragma unroll
      for (int j = 0; j < 8; j++) vv[j] = act[(u32)sb[j]*CIN + k];
      #pragma unroll
      for (int j = 0; j < 8; j++) acc = fmaf(wb[j], bf2f(vv[j]), acc);
    }
  }
  #pragma unroll
  for (int st = H; st < 64; st <<= 1) den_lane += __shfl_xor(den_lane, st);
  float den = __shfl(den_lane, hf);
  if (lane < LX)
    D[(u32)wid*LX + fl] = f2bf(acc / (den + 1e-16f));
}

// ---------------- fused column stats: partials + last-block fold ----------------
template<int F,int TPB>
__global__ __launch_bounds__(TPB) void k_statAB(const u16* __restrict__ x, int n,
    float* __restrict__ part, float* __restrict__ outS, int* __restrict__ cnt)
{
  constexpr int L = F/2;
  constexpr int RPB = TPB/L;
  static_assert(TPB % L == 0, "");
  int c = threadIdx.x % L;
  int tr = threadIdx.x / L;
  const u32* xw = (const u32*)x;
  int chunk = (n + (int)gridDim.x - 1)/(int)gridDim.x;
  int r0 = blockIdx.x*chunk;
  int r1 = r0 + chunk; if (r1 > n) r1 = n;
  float a0=0.f, a1=0.f, b0=0.f, b1=0.f;
  int r = r0 + tr;
  for (; r + 3*RPB < r1; r += 4*RPB){
    u32 v0 = xw[(size_t)r*L + c];
    u32 v1 = xw[(size_t)(r + RPB)*L + c];
    u32 v2 = xw[(size_t)(r + 2*RPB)*L + c];
    u32 v3 = xw[(size_t)(r + 3*RPB)*L + c];
    float f0 = bf2f((u16)v0), f1 = bf2f((u16)(v0 >> 16));
    float f2 = bf2f((u16)v1), f3 = bf2f((u16)(v1 >> 16));
    float f4 = bf2f((u16)v2), f5 = bf2f((u16)(v2 >> 16));
    float f6 = bf2f((u16)v3), f7 = bf2f((u16)(v3 >> 16));
    a0 += (f0 + f2) + (f4 + f6);
    a1 += (f1 + f3) + (f5 + f7);
    b0 += (f0*f0 + f2*f2) + (f4*f4 + f6*f6);
    b1 += (f1*f1 + f3*f3) + (f5*f5 + f7*f7);
  }
  for (; r < r1; r += RPB){
    u32 v = xw[(size_t)r*L + c];
    float f0 = bf2f((u16)v), f1 = bf2f((u16)(v >> 16));
    a0 += f0; b0 = fmaf(f0, f0, b0);
    a1 += f1; b1 = fmaf(f1, f1, b1);
  }
  __shared__ float l0[TPB], l1[TPB], l2[TPB], l3[TPB];
  l0[threadIdx.x] = a0; l1[threadIdx.x] = a1;
  l2[threadIdx.x] = b0; l3[threadIdx.x] = b1;
  __syncthreads();
  for (int t2 = threadIdx.x; t2 < 256; t2 += TPB){
    int col = t2 & 127;
    float s = 0.f;
    if (col < F){
      int cc = col >> 1, par = col & 1;
      const float* base = (t2 >= 128) ? (par ? l3 : l2) : (par ? l1 : l0);
      #pragma unroll 4
      for (int j = 0; j < RPB; j++) s += base[j*L + cc];
    }
    part[(size_t)blockIdx.x*256 + t2] = s;
  }
  __threadfence();
  __shared__ int lastf;
  if (threadIdx.x == 0) lastf = (atomicAdd(cnt, 1) == (int)gridDim.x - 1) ? 1 : 0;
  __syncthreads();
  if (lastf){
    __threadfence();
    for (int t2 = threadIdx.x; t2 < 256; t2 += TPB){
      float s = 0.f;
      int b = 0;
      for (; b + 3 < PST; b += 4)
        s += (part[(size_t)b*256 + t2] + part[(size_t)(b+1)*256 + t2])
           + (part[(size_t)(b+2)*256 + t2] + part[(size_t)(b+3)*256 + t2]);
      for (; b < PST; b++) s += part[(size_t)b*256 + t2];
      outS[t2] = s;
    }
  }
}

// ---------------- pool per graph + classifier ----------------
__global__ __launch_bounds__(256) void k_pool(const u16* B, const int* batch, int n,
    const float* stat, const void* g3, const void* be3, float invn,
    const void* Wo, const void* bo, void* outp, const int* dflag)
{
  const int f32 = dflag[0];
  __shared__ float fa[64], fd[64];
  if (threadIdx.x < 64){
    int k = threadIdx.x;
    float m = stat[k]*invn;
    float v = stat[128 + k]*invn - m*m;
    float a = gload(g3, k, f32) * rsqrtf(v + 1e-5f);
    fa[k] = a;
    fd[k] = gload(be3, k, f32) - m*a;
  }
  __syncthreads();

  int g = blockIdx.x;
  int lane = threadIdx.x & 63, wv = threadIdx.x >> 6;
  int s, e;
  { int l = 0, h = n; while (l < h){ int m = (l+h)>>1; if (batch[m] <  g) l = m+1; else h = m; } s = l; }
  { int l = s, h = n; while (l < h){ int m = (l+h)>>1; if (batch[m] <= g) l = m+1; else h = m; } e = l; }
  float a = fa[lane], d = fd[lane], acc = 0.f;
  for (int r = s + wv; r < e; r += 4)
    acc += fmaxf(fmaf(a, bf2f(B[(size_t)r*64 + lane]), d), 0.f);
  __shared__ float pl[4][64];
  pl[wv][lane] = acc;
  __syncthreads();
  if (wv == 0){
    float cnt = (e > s) ? (float)(e - s) : 1.f;
    pl[0][lane] = (pl[0][lane] + pl[1][lane] + pl[2][lane] + pl[3][lane]) / cnt;
  }
  __syncthreads();
  if (threadIdx.x < 10){
    int lo = threadIdx.x;
    float o = gload(bo, lo, f32);
    for (int l2 = 0; l2 < 64; l2++) o = fmaf(pl[0][l2], gload(Wo, l2*10 + lo, f32), o);
    if (f32) ((float*)outp)[g*10 + lo] = o;
    else     ((u16*) outp)[g*10 + lo] = f2bf(o);
  }
}

// ---------------- launch ----------------
extern "C" void kernel_launch(void* const* d_in, const int* in_sizes, int n_in,
                              void* d_out, int out_size, void* d_ws, size_t ws_size,
                              hipStream_t stream)
{
  const void* x   = d_in[0];
  const int* ei   = (const int*)d_in[1];
  const int* batch= (const int*)d_in[2];
  const void* W1  = d_in[3];
  const void* as1 = d_in[4];
  const void* ad1 = d_in[5];
  const void* g1  = d_in[7];
  const void* be1 = d_in[8];
  const void* Wl1 = d_in[9];
  const void* gl1 = d_in[11];
  const void* bel1= d_in[12];
  const void* W2  = d_in[13];
  const void* as2 = d_in[14];
  const void* ad2 = d_in[15];
  const void* g2  = d_in[17];
  const void* be2 = d_in[18];
  const void* Wl2 = d_in[19];
  const void* gl2 = d_in[21];
  const void* bel2= d_in[22];
  const void* W3  = d_in[23];
  const void* as3 = d_in[24];
  const void* ad3 = d_in[25];
  const void* g3  = d_in[27];
  const void* be3 = d_in[28];
  const void* Wo  = d_in[29];
  const void* bo  = d_in[30];
  (void)n_in; (void)ws_size;

  const int N = in_sizes[2];
  const int E = in_sizes[1] / 2;
  const int G = out_size / 10;
  const int NB = (N + NPB - 1) >> SHB;

  char* w = (char*)d_ws;
  size_t off = 0;
  auto alloc = [&](size_t bytes)->void*{
    size_t o = off; off += (bytes + 255) & ~(size_t)255; return (void*)(w + o);
  };
  int*   dflag= (int*)alloc(4);
  int*   cnts = (int*)alloc(8*4);
  int*   coff = (int*)alloc((size_t)(N+1)*4);
  int*   csr  = (int*)alloc((size_t)E*4);
  int*   bbase= (int*)alloc((size_t)(NB+1)*4);
  int*   btot = (int*)alloc((size_t)NB*4);
  int*   hist = (int*)alloc((size_t)BHB*NB*4);
  float* stS  = (float*)alloc(1280*4);
  float* part = (float*)alloc((size_t)PST*256*4);
  float* prepF= (float*)alloc(256*4);
  u16*   Wt   = (u16*)alloc(128*128*2);
  u16*   Wbd2 = (u16*)alloc(64*96*2);
  u16*   Wbd3 = (u16*)alloc(48*64*2);
  u16*   als  = (u16*)alloc((size_t)N*8*2);
  u16*   ald  = (u16*)alloc((size_t)N*8*2);
  u16*   Cb   = (u16*)alloc((size_t)N*24*2);
  u16*   A    = (u16*)alloc((size_t)N*128*2);
  u16*   B    = (u16*)alloc((size_t)N*128*2);
  u32*   tmp  = (u32*)A;
  u16*   D    = A;
  u16*   act  = A + (size_t)N*64;

  const float invN = 1.f/(float)N;
  const int nbw = (NB + 3)/4;

  k_prep<<<18, 256, 0, stream>>>(x, W1, W2, as2, ad2, W3, as3, ad3,
                                 dflag, Wt, Wbd2, Wbd3, prepF, cnts);

  k_bhist<<<BHB, 1024, 0, stream>>>(ei, E, hist, NB);
  k_btotW<<<nbw, 256, 0, stream>>>(hist, btot, NB);
  k_bscan<<<1, 512, 0, stream>>>(btot, bbase, coff, NB, N);
  k_bcurW<<<nbw, 256, 0, stream>>>(hist, bbase, NB);
  k_bfill<<<BHB, 1024, 0, stream>>>(ei, E, hist, tmp, NB);
  k_cfill<<<NB, 256, 0, stream>>>(tmp, bbase, coff, csr, N);

  k_mfma1A<<<(N+63)/64, 256, 0, stream>>>(x, Wt, as1, ad1, A, als, ald, N, dflag);
  k_pullW<8,16><<<(N+3)/4, 256, 0, stream>>>(A, als, ald, coff, csr, B, N);
  k_statAB<128,256><<<PST, 256, 0, stream>>>(B, N, part, stS + 0, cnts + 0);

  k_gemm<128,16,1,256,true,false><<<(N+63)/64, 256, 0, stream>>>(
      B, Wl1, stS + 0, g1, be1, invN, Cb, N, dflag);
  k_statAB<16,256><<<PST, 256, 0, stream>>>(Cb, N, part, stS + 256, cnts + 1);

  k_alphaX<4,16><<<(N*4+255)/256, 256, 0, stream>>>(
      Cb, stS + 256, gl1, bel1, invN, prepF + 0, prepF + 64, act, als, ald, N, dflag);
  k_pullX<4,16><<<(N+3)/4, 256, 0, stream>>>(act, als, ald, coff, csr, D, N);
  k_gemm<64,96,2,192,false,true><<<(N+15)/16, 192, 0, stream>>>(
      D, Wbd2, nullptr, nullptr, nullptr, invN, B, N, dflag);
  k_statAB<96,192><<<PST, 192, 0, stream>>>(B, N, part, stS + 512, cnts + 2);

  k_gemm<96,24,2,192,true,false><<<(N+63)/64, 192, 0, stream>>>(
      B, Wl2, stS + 512, g2, be2, invN, Cb, N, dflag);
  k_statAB<24,192><<<PST, 192, 0, stream>>>(Cb, N, part, stS + 768, cnts + 3);

  k_alphaX<2,24><<<(N*2+255)/256, 256, 0, stream>>>(
      Cb, stS + 768, gl2, bel2, invN, prepF + 128, prepF + 176, act, als, ald, N, dflag);
  k_pullX<2,24><<<(N+3)/4, 256, 0, stream>>>(act, als, ald, coff, csr, D, N);
  k_gemm<48,64,2,256,false,true><<<(N+31)/32, 256, 0, stream>>>(
      D, Wbd3, nullptr, nullptr, nullptr, invN, B, N, dflag);
  k_statAB<64,256><<<PST, 256, 0, stream>>>(B, N, part, stS + 1024, cnts + 4);

  k_pool<<<G, 256, 0, stream>>>(B, batch, N, stS + 1024, g3, be3, invN, Wo, bo, d_out, dflag);
}